// Round 18
// baseline (232.886 us; speedup 1.0000x reference)
//
#include <hip/hip_runtime.h>
#include <hip/hip_bf16.h>
#include <cmath>

#define N_TOK 32768
#define DIM   256
#define NEXP  8
#define HID   1024
#define BM    64
#define BH    64
#define MAXT  512   // MAXT*BM == N_TOK: covers worst-case expert load

typedef short bf16x8 __attribute__((ext_vector_type(8)));
typedef float f32x4  __attribute__((ext_vector_type(4)));

__device__ __forceinline__ ushort f2bf(float f) {
  unsigned u = __builtin_bit_cast(unsigned, f);
  u += 0x7fffu + ((u >> 16) & 1u);   // RNE
  return (ushort)(u >> 16);
}

// lh swizzle (128B rows): 16B-slot XOR, max 112 < 128 -> bijective in-row.
__device__ __forceinline__ int lh_slot(int row) {
  return ((row ^ (row >> 3)) & 7) << 4;
}
// lx swizzle (512B rows): (r&7)<<4, max 112 < 512, bijective.
__device__ __forceinline__ int lx_slot(int row) {
  return (row & 7) << 4;
}

// ---------- transpose + cast: src[E][R][C] f32 -> dst[E][C][R] bf16 ----------
__global__ __launch_bounds__(256) void k_transpose_cast(
    const float* __restrict__ src, ushort* __restrict__ dst, int R, int C)
{
  __shared__ float tile[32][33];
  int e = blockIdx.z, rb = blockIdx.y, cb = blockIdx.x;
  int tx = threadIdx.x, ty = threadIdx.y;           // 32 x 8
  const float* s = src + (size_t)e * R * C;
  ushort* d = dst + (size_t)e * R * C;
#pragma unroll
  for (int j = 0; j < 4; ++j)
    tile[ty + 8*j][tx] = s[(size_t)(rb*32 + ty + 8*j) * C + cb*32 + tx];
  __syncthreads();
#pragma unroll
  for (int j = 0; j < 4; ++j)
    d[(size_t)(cb*32 + ty + 8*j) * R + rb*32 + tx] = f2bf(tile[tx][ty + 8*j]);
}

// ---------- router: fp64 logits, softmax, top-2, bucket scatter ----------
// tok entry packs the top-k slot in bit 30: n | (slot<<30).
__global__ __launch_bounds__(256) void k_router(
    const float* __restrict__ x, const float* __restrict__ grad,
    const float* __restrict__ Wr, const float* __restrict__ br,
    float* __restrict__ probs_out,
    int* __restrict__ cnt, int* __restrict__ tok, float* __restrict__ wgt)
{
  __shared__ float xt[256][33];
  __shared__ float wrs[257*8];
  __shared__ float brs[8];
  __shared__ int lcnt[8], lbase[8];
  int tid = threadIdx.x;
  int n = blockIdx.x * 256 + tid;

  for (int i = tid; i < 257*8; i += 256) wrs[i] = Wr[i];
  if (tid < 8) { brs[tid] = br[tid]; lcnt[tid] = 0; }

  double acc[8] = {0,0,0,0,0,0,0,0};
  for (int ch = 0; ch < 8; ++ch) {
    __syncthreads();
    for (int f = tid; f < 2048; f += 256) {
      int r = f >> 3, c0 = (f & 7) * 4;
      float4 v = *(const float4*)(x + (size_t)(blockIdx.x*256 + r)*DIM + ch*32 + c0);
      xt[r][c0] = v.x; xt[r][c0+1] = v.y; xt[r][c0+2] = v.z; xt[r][c0+3] = v.w;
    }
    __syncthreads();
#pragma unroll 4
    for (int c = 0; c < 32; ++c) {
      double xv = (double)xt[tid][c];
      const float* wr = &wrs[(ch*32 + c)*8];
#pragma unroll
      for (int e = 0; e < 8; ++e) acc[e] += xv * (double)wr[e];
    }
  }
  double g = (double)grad[n];
  double lg[8];
#pragma unroll
  for (int e = 0; e < 8; ++e) lg[e] = acc[e] + g*(double)wrs[256*8+e] + (double)brs[e];
  double m = lg[0];
#pragma unroll
  for (int e = 1; e < 8; ++e) m = lg[e] > m ? lg[e] : m;
  double p[8], s = 0.0;
#pragma unroll
  for (int e = 0; e < 8; ++e) { p[e] = exp(lg[e]-m); s += p[e]; }
  double inv = 1.0/s;
#pragma unroll
  for (int e = 0; e < 8; ++e) probs_out[(size_t)n*8 + e] = (float)(p[e]*inv);

  int i0 = 0;
#pragma unroll
  for (int e = 1; e < 8; ++e) if (lg[e] > lg[i0]) i0 = e;
  int i1 = (i0 == 0) ? 1 : 0;
#pragma unroll
  for (int e = 0; e < 8; ++e) if (e != i0 && lg[e] > lg[i1]) i1 = e;
  float w0 = (float)(p[i0]*inv), w1 = (float)(p[i1]*inv);

  int p0 = atomicAdd(&lcnt[i0], 1);
  int p1 = atomicAdd(&lcnt[i1], 1);
  __syncthreads();
  if (tid < 8) lbase[tid] = atomicAdd(&cnt[tid], lcnt[tid]);
  __syncthreads();
  tok[i0*N_TOK + lbase[i0] + p0] = n;              wgt[i0*N_TOK + lbase[i0] + p0] = w0;
  tok[i1*N_TOK + lbase[i1] + p1] = n | (1 << 30);  wgt[i1*N_TOK + lbase[i1] + p1] = w1;
}

// ---------- fused gathered expert MLP ----------
// r18 = r17 config with 48 KB LDS (lsB dropped, single W1 buffer staged into
// the dead x-tile after barrier A — r13's loop body, correctness-validated).
// KEY: __launch_bounds__(256,2) — the allocator then produces 128 VGPR with
// ZERO spill (5 rounds of evidence); residency is LDS-limited: 48 KB -> 3
// blocks/CU = 12 waves (was 8). Do NOT use (256,3)/waves_per_eu to force
// occupancy: both made the allocator target 6 waves/EU -> 84 VGPR -> scratch
// spills (FETCH 450 MB, 2.4x slower; r13/r14).
// e = bid&7: weights L2-resident. GELU via LDS LUT. Slab epilogue. Stagger.
template<int SLAB>
__global__ __launch_bounds__(256, 2) void k_moe(
    const float* __restrict__ x,
    const ushort* __restrict__ w1t,   // [E][H][D] bf16 (transposed)
    const ushort* __restrict__ w2t,   // [E][D][H] bf16 (transposed)
    const float* __restrict__ bias1,  // [E][H]
    const float* __restrict__ bias2,  // [E][D]
    const int* __restrict__ cnt, const int* __restrict__ tok,
    const float* __restrict__ wgt,
    float* __restrict__ out, float* __restrict__ slab)
{
  int e    = blockIdx.x & 7;
  int tile = blockIdx.x >> 3;
  int c = cnt[e];
  int row0 = tile * BM;
  if (row0 >= c) return;
  int rows = min(BM, c - row0);
  int phase = tile & 15;              // stagger concurrent blocks across W chunks

  __shared__ ushort lsA[BM * DIM];    // 32 KB: x tile, then the W1 buffer
  __shared__ ushort lh[BM * BH];      // 8 KB h tile
  __shared__ float  lb1[HID];         // 4 KB bias1
  __shared__ float2 lut[512];         // 4 KB gelu LUT: g(v) ~= a + b*v, v in [-8,8]
  // total 48 KB -> 3 blocks/CU (128 VGPR allows 4 waves/SIMD; LDS limits to 3)

  int tid  = threadIdx.x;
  int lane = tid & 63;
  int wid  = tid >> 6;
  const int l15 = lane & 15;
  const int lk8 = (lane >> 4) * 8;
  const int lr4 = (lane >> 4) * 4;
  const int wr = wid >> 1, wc = wid & 1;   // 2x2 wave grid for GEMM1

  const int*   etok = tok + e * N_TOK + row0;
  const float* ewgt = wgt + e * N_TOK + row0;
  const ushort* W1e = w1t + (size_t)e * HID * DIM;
  const ushort* W2e = w2t + (size_t)e * DIM * HID;

  // ---- prologue: x -> lsA (swizzled), bias1 -> lb1, LUT ----
  for (int f = tid; f < BM * (DIM/4); f += 256) {
    int r = f >> 6, c4 = f & 63;
    int t = etok[min(r, rows - 1)] & 0xFFFF;
    float4 v = *(const float4*)(x + (size_t)t * DIM + c4 * 4);
    ushort4 b;
    b.x = f2bf(v.x); b.y = f2bf(v.y); b.z = f2bf(v.z); b.w = f2bf(v.w);
    *(ushort4*)((char*)lsA + r * 512 + ((c4 * 8) ^ lx_slot(r))) = b;
  }
#pragma unroll
  for (int i = 0; i < 4; ++i) lb1[i*256 + tid] = bias1[e*HID + i*256 + tid];
  // gelu LUT: segment i covers [v0, v0+1/32), chord endpoints -> exact at knots
  for (int i = tid; i < 512; i += 256) {
    float v0 = i * 0.03125f - 8.0f;
    float v1 = v0 + 0.03125f;
    float g0 = 0.5f * v0 * (1.0f + erff(v0 * 0.70710678f));
    float g1 = 0.5f * v1 * (1.0f + erff(v1 * 0.70710678f));
    float b  = (g1 - g0) * 32.0f;
    lut[i] = make_float2(g0 - b * v0, b);
  }
  __syncthreads();   // x, bias, LUT visible

  // ---- hoist A-fragments to registers once ----
  bf16x8 areg[2][8];
#pragma unroll
  for (int fr = 0; fr < 2; ++fr) {
    int row = wr*32 + fr*16 + l15;
#pragma unroll
    for (int k = 0; k < 8; ++k)
      areg[fr][k] = *(const bf16x8*)((const char*)lsA + row*512
                      + (((k*32 + lk8)*2) ^ lx_slot(row)));
  }
  __syncthreads();   // all areg reads done; lsA becomes the W1 buffer

  // ---- stage W1 chunk0 into lsA ----
  {
    int h0 = (phase & 15) * BH;
#pragma unroll
    for (int i = 0; i < 8; ++i) {
      int u = i*256 + tid;
      int r = u >> 5, s = u & 31;
      const ushort* g = W1e + (size_t)(h0 + r) * DIM + ((s ^ (r & 7)) * 8);
      __builtin_amdgcn_global_load_lds(
          (const __attribute__((address_space(1))) unsigned int*)g,
          (__attribute__((address_space(3))) unsigned int*)(lsA + u*8),
          16, 0, 0);
    }
  }
  __syncthreads();   // chunk0 staged

  f32x4 accY[4][4];
#pragma unroll
  for (int i = 0; i < 4; ++i)
#pragma unroll
    for (int j = 0; j < 4; ++j) accY[i][j] = (f32x4){0.f,0.f,0.f,0.f};

  int sl2[4];
#pragma unroll
  for (int fr = 0; fr < 4; ++fr) sl2[fr] = lh_slot(fr*16 + l15);

  // W1 LDS fragment addressing (ushort units): unit = row*32 + (s ^ (row&7))
  const int b0row = wc*32 + l15;            // b1 row = b0row+16, same (row&7)
  const int bxor  = (b0row & 7);

  for (int cc = 0; cc < HID / BH; ++cc) {
    int chunk = (cc + phase) & 15;
    int h0 = chunk * BH;

    // W2 B-fragments to regs (consumed after barrier A -> latency covered)
    bf16x8 bw[2][4];
#pragma unroll
    for (int k2 = 0; k2 < 2; ++k2)
#pragma unroll
      for (int fc = 0; fc < 4; ++fc)
        bw[k2][fc] = *(const bf16x8*)(W2e + (size_t)(wid*64 + fc*16 + l15) * HID
                                      + h0 + k2*32 + lk8);

    f32x4 accH[2][2];
#pragma unroll
    for (int i = 0; i < 2; ++i)
#pragma unroll
      for (int j = 0; j < 2; ++j) accH[i][j] = (f32x4){0.f,0.f,0.f,0.f};

    // GEMM1: h[64x64] = x[64x256] @ W1[256x64]; B from lsA (conflict-free)
#pragma unroll
    for (int k = 0; k < 8; ++k) {
      int s = k*4 + (lane >> 4);
      bf16x8 b0 = *(const bf16x8*)(lsA + ((b0row     )*32 + (s ^ bxor))*8);
      bf16x8 b1 = *(const bf16x8*)(lsA + ((b0row + 16)*32 + (s ^ bxor))*8);
      accH[0][0] = __builtin_amdgcn_mfma_f32_16x16x32_bf16(areg[0][k], b0, accH[0][0], 0, 0, 0);
      accH[1][0] = __builtin_amdgcn_mfma_f32_16x16x32_bf16(areg[1][k], b0, accH[1][0], 0, 0, 0);
      accH[0][1] = __builtin_amdgcn_mfma_f32_16x16x32_bf16(areg[0][k], b1, accH[0][1], 0, 0, 0);
      accH[1][1] = __builtin_amdgcn_mfma_f32_16x16x32_bf16(areg[1][k], b1, accH[1][1], 0, 0, 0);
    }

    // GELU (LUT) + bf16 -> swizzled lh
#pragma unroll
    for (int fc = 0; fc < 2; ++fc) {
      int col = wc*32 + fc*16 + l15;
      float bv = lb1[h0 + col];
#pragma unroll
      for (int fr = 0; fr < 2; ++fr)
#pragma unroll
        for (int j = 0; j < 4; ++j) {
          int row = wr*32 + fr*16 + lr4 + j;
          float v = accH[fr][fc][j] + bv;
          int idx = (int)(v * 32.0f + 256.0f);
          idx = min(max(idx, 0), 511);
          float2 ab = lut[idx];
          float g = fmaf(ab.y, v, ab.x);
          *(ushort*)((char*)lh + row*128 + ((col*2) ^ lh_slot(row))) = f2bf(g);
        }
    }
    __syncthreads();   // barrier A: lh visible; all GEMM1 reads of lsA done

    // stage W1 for chunk cc+1 into lsA (drains at barrier B; covered by GEMM2
    // intra-block + cross-block waves at 3 blocks/CU)
    if (cc < HID/BH - 1) {
      int nh0 = ((cc + 1 + phase) & 15) * BH;
#pragma unroll
      for (int i = 0; i < 8; ++i) {
        int u = i*256 + tid;
        int r = u >> 5, s = u & 31;
        const ushort* g = W1e + (size_t)(nh0 + r) * DIM + ((s ^ (r & 7)) * 8);
        __builtin_amdgcn_global_load_lds(
            (const __attribute__((address_space(1))) unsigned int*)g,
            (__attribute__((address_space(3))) unsigned int*)(lsA + u*8),
            16, 0, 0);
      }
    }

    // GEMM2: y[64x256] += h[64x64] @ W2[64x256]
#pragma unroll
    for (int k2 = 0; k2 < 2; ++k2) {
      bf16x8 a2[4];
#pragma unroll
      for (int fr = 0; fr < 4; ++fr) {
        int row = fr*16 + l15;
        a2[fr] = *(const bf16x8*)((const char*)lh + row*128 + (((k2*32 + lk8)*2) ^ sl2[fr]));
      }
#pragma unroll
      for (int fr = 0; fr < 4; ++fr)
#pragma unroll
        for (int fc = 0; fc < 4; ++fc)
          accY[fr][fc] = __builtin_amdgcn_mfma_f32_16x16x32_bf16(a2[fr], bw[k2][fc], accY[fr][fc], 0, 0, 0);
    }
    __syncthreads();   // barrier B: stage drained + lh reads done
  }

  // epilogue: contribution = w * (y + b2)
  float b2v[4];
#pragma unroll
  for (int fc = 0; fc < 4; ++fc) b2v[fc] = bias2[e*DIM + wid*64 + fc*16 + l15];
#pragma unroll
  for (int fr = 0; fr < 4; ++fr) {
#pragma unroll
    for (int j = 0; j < 4; ++j) {
      int r = fr*16 + lr4 + j;
      if (r < rows) {
        int raw = etok[r];
        int t   = raw & 0xFFFF;
        float w = ewgt[r];
        if (SLAB) {
          // each (token,slot) written by exactly one block -> plain stores;
          // out (slot0) and slab (slot1) are FULLY covered -> no memset needed
          float* dst = ((raw >> 30) ? slab : out) + (size_t)t * DIM;
#pragma unroll
          for (int fc = 0; fc < 4; ++fc)
            dst[wid*64 + fc*16 + l15] = w * (accY[fr][fc][j] + b2v[fc]);
        } else {
#pragma unroll
          for (int fc = 0; fc < 4; ++fc)
            atomicAdd(out + (size_t)t * DIM + wid*64 + fc*16 + l15,
                      w * (accY[fr][fc][j] + b2v[fc]));
        }
      }
    }
  }
}

// out += slab (slab fully written: every token has exactly one slot-1 entry)
__global__ __launch_bounds__(256) void k_combine(
    float* __restrict__ out, const float* __restrict__ slab)
{
  int stride = gridDim.x * blockDim.x;
  for (int i = blockIdx.x * blockDim.x + threadIdx.x;
       i < N_TOK * DIM / 4; i += stride) {
    float4 a = ((const float4*)out)[i];
    float4 b = ((const float4*)slab)[i];
    a.x += b.x; a.y += b.y; a.z += b.z; a.w += b.w;
    ((float4*)out)[i] = a;
  }
}

extern "C" void kernel_launch(void* const* d_in, const int* in_sizes, int n_in,
                              void* d_out, int out_size, void* d_ws, size_t ws_size,
                              hipStream_t stream)
{
  const float* x    = (const float*)d_in[0];
  const float* grad = (const float*)d_in[1];
  const float* Wr   = (const float*)d_in[2];
  const float* br   = (const float*)d_in[3];
  const float* W1   = (const float*)d_in[4];
  const float* b1   = (const float*)d_in[5];
  const float* W2   = (const float*)d_in[6];
  const float* b2   = (const float*)d_in[7];
  float* out   = (float*)d_out;
  float* probs = out + (size_t)N_TOK * DIM;

  char* wsb = (char*)d_ws;
  int*    cnt = (int*)wsb;                                        // 32 B
  int*    tok = (int*)   (wsb + 4096);                            // 1 MB
  float*  wgt = (float*) (wsb + 4096 + (size_t)NEXP*N_TOK*4);     // 1 MB
  ushort* w1t = (ushort*)(wsb + 4096 + (size_t)NEXP*N_TOK*8);     // 4 MB
  ushort* w2t = w1t + (size_t)NEXP * HID * DIM;                   // 4 MB
  float*  slab = (float*)(wsb + (size_t)(16 << 20));              // 32 MB @ +16MB

  bool use_slab = ws_size >= ((size_t)(16 << 20) + (size_t)N_TOK * DIM * 4);

  hipMemsetAsync(cnt, 0, NEXP * sizeof(int), stream);
  if (!use_slab)   // slab mode fully overwrites out; atomic fallback accumulates
    hipMemsetAsync(d_out, 0, (size_t)N_TOK * DIM * sizeof(float), stream);

  k_transpose_cast<<<dim3(HID/32, DIM/32, NEXP), dim3(32, 8), 0, stream>>>(W1, w1t, DIM, HID);
  k_transpose_cast<<<dim3(DIM/32, HID/32, NEXP), dim3(32, 8), 0, stream>>>(W2, w2t, HID, DIM);
  k_router<<<N_TOK/256, 256, 0, stream>>>(x, grad, Wr, br, probs, cnt, tok, wgt);
  if (use_slab) {
    k_moe<1><<<NEXP*MAXT, 256, 0, stream>>>(x, w1t, w2t, b1, b2, cnt, tok, wgt, out, slab);
    k_combine<<<2048, 256, 0, stream>>>(out, slab);
  } else {
    k_moe<0><<<NEXP*MAXT, 256, 0, stream>>>(x, w1t, w2t, b1, b2, cnt, tok, wgt, out, slab);
  }
}

// Round 19
// 217.855 us; speedup vs baseline: 1.0690x; 1.0690x over previous
//
#include <hip/hip_runtime.h>
#include <hip/hip_bf16.h>
#include <cmath>

#define N_TOK 32768
#define DIM   256
#define NEXP  8
#define HID   1024
#define BM    64
#define BH    64
#define MAXT  512   // MAXT*BM == N_TOK: covers worst-case expert load

typedef short bf16x8 __attribute__((ext_vector_type(8)));
typedef float f32x4  __attribute__((ext_vector_type(4)));

__device__ __forceinline__ ushort f2bf(float f) {
  unsigned u = __builtin_bit_cast(unsigned, f);
  u += 0x7fffu + ((u >> 16) & 1u);   // RNE
  return (ushort)(u >> 16);
}

// lh swizzle (128B rows): 16B-slot XOR, max 112 < 128 -> bijective in-row.
__device__ __forceinline__ int lh_slot(int row) {
  return ((row ^ (row >> 3)) & 7) << 4;
}
// lx swizzle (512B rows): (r&7)<<4, max 112 < 512, bijective.
__device__ __forceinline__ int lx_slot(int row) {
  return (row & 7) << 4;
}

// ---------- transpose + cast: src[E][R][C] f32 -> dst[E][C][R] bf16 ----------
__global__ __launch_bounds__(256) void k_transpose_cast(
    const float* __restrict__ src, ushort* __restrict__ dst, int R, int C)
{
  __shared__ float tile[32][33];
  int e = blockIdx.z, rb = blockIdx.y, cb = blockIdx.x;
  int tx = threadIdx.x, ty = threadIdx.y;           // 32 x 8
  const float* s = src + (size_t)e * R * C;
  ushort* d = dst + (size_t)e * R * C;
#pragma unroll
  for (int j = 0; j < 4; ++j)
    tile[ty + 8*j][tx] = s[(size_t)(rb*32 + ty + 8*j) * C + cb*32 + tx];
  __syncthreads();
#pragma unroll
  for (int j = 0; j < 4; ++j)
    d[(size_t)(cb*32 + ty + 8*j) * R + rb*32 + tx] = f2bf(tile[tx][ty + 8*j]);
}

// ---------- router: fp64 logits, softmax, top-2, bucket scatter ----------
// tok entry packs the top-k slot in bit 30: n | (slot<<30).
__global__ __launch_bounds__(256) void k_router(
    const float* __restrict__ x, const float* __restrict__ grad,
    const float* __restrict__ Wr, const float* __restrict__ br,
    float* __restrict__ probs_out,
    int* __restrict__ cnt, int* __restrict__ tok, float* __restrict__ wgt)
{
  __shared__ float xt[256][33];
  __shared__ float wrs[257*8];
  __shared__ float brs[8];
  __shared__ int lcnt[8], lbase[8];
  int tid = threadIdx.x;
  int n = blockIdx.x * 256 + tid;

  for (int i = tid; i < 257*8; i += 256) wrs[i] = Wr[i];
  if (tid < 8) { brs[tid] = br[tid]; lcnt[tid] = 0; }

  double acc[8] = {0,0,0,0,0,0,0,0};
  for (int ch = 0; ch < 8; ++ch) {
    __syncthreads();
    for (int f = tid; f < 2048; f += 256) {
      int r = f >> 3, c0 = (f & 7) * 4;
      float4 v = *(const float4*)(x + (size_t)(blockIdx.x*256 + r)*DIM + ch*32 + c0);
      xt[r][c0] = v.x; xt[r][c0+1] = v.y; xt[r][c0+2] = v.z; xt[r][c0+3] = v.w;
    }
    __syncthreads();
#pragma unroll 4
    for (int c = 0; c < 32; ++c) {
      double xv = (double)xt[tid][c];
      const float* wr = &wrs[(ch*32 + c)*8];
#pragma unroll
      for (int e = 0; e < 8; ++e) acc[e] += xv * (double)wr[e];
    }
  }
  double g = (double)grad[n];
  double lg[8];
#pragma unroll
  for (int e = 0; e < 8; ++e) lg[e] = acc[e] + g*(double)wrs[256*8+e] + (double)brs[e];
  double m = lg[0];
#pragma unroll
  for (int e = 1; e < 8; ++e) m = lg[e] > m ? lg[e] : m;
  double p[8], s = 0.0;
#pragma unroll
  for (int e = 0; e < 8; ++e) { p[e] = exp(lg[e]-m); s += p[e]; }
  double inv = 1.0/s;
#pragma unroll
  for (int e = 0; e < 8; ++e) probs_out[(size_t)n*8 + e] = (float)(p[e]*inv);

  int i0 = 0;
#pragma unroll
  for (int e = 1; e < 8; ++e) if (lg[e] > lg[i0]) i0 = e;
  int i1 = (i0 == 0) ? 1 : 0;
#pragma unroll
  for (int e = 0; e < 8; ++e) if (e != i0 && lg[e] > lg[i1]) i1 = e;
  float w0 = (float)(p[i0]*inv), w1 = (float)(p[i1]*inv);

  int p0 = atomicAdd(&lcnt[i0], 1);
  int p1 = atomicAdd(&lcnt[i1], 1);
  __syncthreads();
  if (tid < 8) lbase[tid] = atomicAdd(&cnt[tid], lcnt[tid]);
  __syncthreads();
  tok[i0*N_TOK + lbase[i0] + p0] = n;              wgt[i0*N_TOK + lbase[i0] + p0] = w0;
  tok[i1*N_TOK + lbase[i1] + p1] = n | (1 << 30);  wgt[i1*N_TOK + lbase[i1] + p1] = w1;
}

// ---------- fused gathered expert MLP ----------
// FINAL VALIDATED OPTIMUM (r17: k_moe 167.7us, total 217us). Evidence ledger:
//  * (256,2): allocator gives 128 VGPR, zero spill. ANY occupancy-forcing
//    ((256,3), waves_per_eu(3,3)) makes it target 6 waves/EU -> 84 VGPR ->
//    scratch spills (FETCH 450 MB, 2.4x slower; r13/r14).
//  * 48 KB LDS does NOT raise residency (r18: occupancy flat, dbuf lost,
//    +17us) -> 80 KB double-buffered is strictly better.
//  * e = bid&7: weights L2-resident per XCD (FETCH 69->40 MB, r7).
//  * W1 staged via global_load_lds, double-buffered, issued at chunk top
//    (r9/r10: 321->188us with slab epilogue).
//  * GELU via 512-entry LDS LUT (r11: VALUBusy 42->21%, 188->168us).
//  * __syncthreads barriers; asm counted-vmcnt regressed (r12, +20us).
//  * setprio regressed on this lockstep structure (r15, +9us).
//  * wave-local-h restructure regressed (r16: serial bpermute chain, ~400us).
template<int SLAB>
__global__ __launch_bounds__(256, 2) void k_moe(
    const float* __restrict__ x,
    const ushort* __restrict__ w1t,   // [E][H][D] bf16 (transposed)
    const ushort* __restrict__ w2t,   // [E][D][H] bf16 (transposed)
    const float* __restrict__ bias1,  // [E][H]
    const float* __restrict__ bias2,  // [E][D]
    const int* __restrict__ cnt, const int* __restrict__ tok,
    const float* __restrict__ wgt,
    float* __restrict__ out, float* __restrict__ slab)
{
  int e    = blockIdx.x & 7;
  int tile = blockIdx.x >> 3;
  int c = cnt[e];
  int row0 = tile * BM;
  if (row0 >= c) return;
  int rows = min(BM, c - row0);
  int phase = tile & 15;              // stagger concurrent blocks across W chunks

  __shared__ ushort lsA[BM * DIM];    // 32 KB: x tile, then W1 buffer (odd chunks)
  __shared__ ushort lsB[BH * DIM];    // 32 KB: W1 buffer (even chunks)
  __shared__ ushort lh[BM * BH];      // 8 KB h tile
  __shared__ float  lb1[HID];         // 4 KB bias1
  __shared__ float2 lut[512];         // 4 KB gelu LUT: g(v) ~= a + b*v, v in [-8,8]
  // total 80 KB -> 2 blocks/CU

  int tid  = threadIdx.x;
  int lane = tid & 63;
  int wid  = tid >> 6;
  const int l15 = lane & 15;
  const int lk8 = (lane >> 4) * 8;
  const int lr4 = (lane >> 4) * 4;
  const int wr = wid >> 1, wc = wid & 1;   // 2x2 wave grid for GEMM1

  const int*   etok = tok + e * N_TOK + row0;
  const float* ewgt = wgt + e * N_TOK + row0;
  const ushort* W1e = w1t + (size_t)e * HID * DIM;
  const ushort* W2e = w2t + (size_t)e * DIM * HID;

  // ---- prologue: x -> lsA (swizzled), bias1 -> lb1, LUT, W1 chunk0 -> lsB ----
  for (int f = tid; f < BM * (DIM/4); f += 256) {
    int r = f >> 6, c4 = f & 63;
    int t = etok[min(r, rows - 1)] & 0xFFFF;
    float4 v = *(const float4*)(x + (size_t)t * DIM + c4 * 4);
    ushort4 b;
    b.x = f2bf(v.x); b.y = f2bf(v.y); b.z = f2bf(v.z); b.w = f2bf(v.w);
    *(ushort4*)((char*)lsA + r * 512 + ((c4 * 8) ^ lx_slot(r))) = b;
  }
#pragma unroll
  for (int i = 0; i < 4; ++i) lb1[i*256 + tid] = bias1[e*HID + i*256 + tid];
  // gelu LUT: segment i covers [v0, v0+1/32), chord endpoints -> exact at knots
  for (int i = tid; i < 512; i += 256) {
    float v0 = i * 0.03125f - 8.0f;
    float v1 = v0 + 0.03125f;
    float g0 = 0.5f * v0 * (1.0f + erff(v0 * 0.70710678f));
    float g1 = 0.5f * v1 * (1.0f + erff(v1 * 0.70710678f));
    float b  = (g1 - g0) * 32.0f;
    lut[i] = make_float2(g0 - b * v0, b);
  }
  {
    int h0 = (phase & 15) * BH;
#pragma unroll
    for (int i = 0; i < 8; ++i) {
      int u = i*256 + tid;
      int r = u >> 5, s = u & 31;
      const ushort* g = W1e + (size_t)(h0 + r) * DIM + ((s ^ (r & 7)) * 8);
      __builtin_amdgcn_global_load_lds(
          (const __attribute__((address_space(1))) unsigned int*)g,
          (__attribute__((address_space(3))) unsigned int*)(lsB + u*8),
          16, 0, 0);
    }
  }
  __syncthreads();   // full drain: x, LUT, bias, W1 chunk0 all visible

  // ---- hoist A-fragments to registers once ----
  bf16x8 areg[2][8];
#pragma unroll
  for (int fr = 0; fr < 2; ++fr) {
    int row = wr*32 + fr*16 + l15;
#pragma unroll
    for (int k = 0; k < 8; ++k)
      areg[fr][k] = *(const bf16x8*)((const char*)lsA + row*512
                      + (((k*32 + lk8)*2) ^ lx_slot(row)));
  }
  __syncthreads();   // all waves' areg reads done before lsA is restaged as W1

  f32x4 accY[4][4];
#pragma unroll
  for (int i = 0; i < 4; ++i)
#pragma unroll
    for (int j = 0; j < 4; ++j) accY[i][j] = (f32x4){0.f,0.f,0.f,0.f};

  int sl2[4];
#pragma unroll
  for (int fr = 0; fr < 4; ++fr) sl2[fr] = lh_slot(fr*16 + l15);

  // W1 LDS fragment addressing (ushort units): unit = row*32 + (s ^ (row&7))
  const int b0row = wc*32 + l15;            // b1 row = b0row+16, same (row&7)
  const int bxor  = (b0row & 7);

  for (int cc = 0; cc < HID / BH; ++cc) {
    int chunk = (cc + phase) & 15;
    int h0 = chunk * BH;
    ushort* cur = (cc & 1) ? lsA : lsB;
    ushort* nxt = (cc & 1) ? lsB : lsA;

    // W2 B-fragments to regs (consumed after barrier A -> latency covered)
    bf16x8 bw[2][4];
#pragma unroll
    for (int k2 = 0; k2 < 2; ++k2)
#pragma unroll
      for (int fc = 0; fc < 4; ++fc)
        bw[k2][fc] = *(const bf16x8*)(W2e + (size_t)(wid*64 + fc*16 + l15) * HID
                                      + h0 + k2*32 + lk8);

    // stage W1 for chunk cc+1 (drains at barrier A with the chunk's other vm
    // ops; covered by GEMM1 + GELU)
    if (cc < HID/BH - 1) {
      int nh0 = ((cc + 1 + phase) & 15) * BH;
#pragma unroll
      for (int i = 0; i < 8; ++i) {
        int u = i*256 + tid;
        int r = u >> 5, s = u & 31;
        const ushort* g = W1e + (size_t)(nh0 + r) * DIM + ((s ^ (r & 7)) * 8);
        __builtin_amdgcn_global_load_lds(
            (const __attribute__((address_space(1))) unsigned int*)g,
            (__attribute__((address_space(3))) unsigned int*)(nxt + u*8),
            16, 0, 0);
      }
    }

    f32x4 accH[2][2];
#pragma unroll
    for (int i = 0; i < 2; ++i)
#pragma unroll
      for (int j = 0; j < 2; ++j) accH[i][j] = (f32x4){0.f,0.f,0.f,0.f};

    // GEMM1: h[64x64] = x[64x256] @ W1[256x64]; B from cur (conflict-free)
#pragma unroll
    for (int k = 0; k < 8; ++k) {
      int s = k*4 + (lane >> 4);
      bf16x8 b0 = *(const bf16x8*)(cur + ((b0row     )*32 + (s ^ bxor))*8);
      bf16x8 b1 = *(const bf16x8*)(cur + ((b0row + 16)*32 + (s ^ bxor))*8);
      accH[0][0] = __builtin_amdgcn_mfma_f32_16x16x32_bf16(areg[0][k], b0, accH[0][0], 0, 0, 0);
      accH[1][0] = __builtin_amdgcn_mfma_f32_16x16x32_bf16(areg[1][k], b0, accH[1][0], 0, 0, 0);
      accH[0][1] = __builtin_amdgcn_mfma_f32_16x16x32_bf16(areg[0][k], b1, accH[0][1], 0, 0, 0);
      accH[1][1] = __builtin_amdgcn_mfma_f32_16x16x32_bf16(areg[1][k], b1, accH[1][1], 0, 0, 0);
    }

    // GELU (LUT) + bf16 -> swizzled lh
#pragma unroll
    for (int fc = 0; fc < 2; ++fc) {
      int col = wc*32 + fc*16 + l15;
      float bv = lb1[h0 + col];
#pragma unroll
      for (int fr = 0; fr < 2; ++fr)
#pragma unroll
        for (int j = 0; j < 4; ++j) {
          int row = wr*32 + fr*16 + lr4 + j;
          float v = accH[fr][fc][j] + bv;
          int idx = (int)(v * 32.0f + 256.0f);
          idx = min(max(idx, 0), 511);
          float2 ab = lut[idx];
          float g = fmaf(ab.y, v, ab.x);
          *(ushort*)((char*)lh + row*128 + ((col*2) ^ lh_slot(row))) = f2bf(g);
        }
    }
    __syncthreads();   // barrier A: lh visible; stage + bw drained (covered)

    // GEMM2: y[64x256] += h[64x64] @ W2[64x256]
#pragma unroll
    for (int k2 = 0; k2 < 2; ++k2) {
      bf16x8 a2[4];
#pragma unroll
      for (int fr = 0; fr < 4; ++fr) {
        int row = fr*16 + l15;
        a2[fr] = *(const bf16x8*)((const char*)lh + row*128 + (((k2*32 + lk8)*2) ^ sl2[fr]));
      }
#pragma unroll
      for (int fr = 0; fr < 4; ++fr)
#pragma unroll
        for (int fc = 0; fc < 4; ++fc)
          accY[fr][fc] = __builtin_amdgcn_mfma_f32_16x16x32_bf16(a2[fr], bw[k2][fc], accY[fr][fc], 0, 0, 0);
    }
    __syncthreads();   // barrier B: lh reusable (vm-free -> cheap)
  }

  // epilogue: contribution = w * (y + b2)
  float b2v[4];
#pragma unroll
  for (int fc = 0; fc < 4; ++fc) b2v[fc] = bias2[e*DIM + wid*64 + fc*16 + l15];
#pragma unroll
  for (int fr = 0; fr < 4; ++fr) {
#pragma unroll
    for (int j = 0; j < 4; ++j) {
      int r = fr*16 + lr4 + j;
      if (r < rows) {
        int raw = etok[r];
        int t   = raw & 0xFFFF;
        float w = ewgt[r];
        if (SLAB) {
          // each (token,slot) written by exactly one block -> plain stores;
          // out (slot0) and slab (slot1) are FULLY covered -> no memset needed
          float* dst = ((raw >> 30) ? slab : out) + (size_t)t * DIM;
#pragma unroll
          for (int fc = 0; fc < 4; ++fc)
            dst[wid*64 + fc*16 + l15] = w * (accY[fr][fc][j] + b2v[fc]);
        } else {
#pragma unroll
          for (int fc = 0; fc < 4; ++fc)
            atomicAdd(out + (size_t)t * DIM + wid*64 + fc*16 + l15,
                      w * (accY[fr][fc][j] + b2v[fc]));
        }
      }
    }
  }
}

// out += slab (slab fully written: every token has exactly one slot-1 entry)
__global__ __launch_bounds__(256) void k_combine(
    float* __restrict__ out, const float* __restrict__ slab)
{
  int stride = gridDim.x * blockDim.x;
  for (int i = blockIdx.x * blockDim.x + threadIdx.x;
       i < N_TOK * DIM / 4; i += stride) {
    float4 a = ((const float4*)out)[i];
    float4 b = ((const float4*)slab)[i];
    a.x += b.x; a.y += b.y; a.z += b.z; a.w += b.w;
    ((float4*)out)[i] = a;
  }
}

extern "C" void kernel_launch(void* const* d_in, const int* in_sizes, int n_in,
                              void* d_out, int out_size, void* d_ws, size_t ws_size,
                              hipStream_t stream)
{
  const float* x    = (const float*)d_in[0];
  const float* grad = (const float*)d_in[1];
  const float* Wr   = (const float*)d_in[2];
  const float* br   = (const float*)d_in[3];
  const float* W1   = (const float*)d_in[4];
  const float* b1   = (const float*)d_in[5];
  const float* W2   = (const float*)d_in[6];
  const float* b2   = (const float*)d_in[7];
  float* out   = (float*)d_out;
  float* probs = out + (size_t)N_TOK * DIM;

  char* wsb = (char*)d_ws;
  int*    cnt = (int*)wsb;                                        // 32 B
  int*    tok = (int*)   (wsb + 4096);                            // 1 MB
  float*  wgt = (float*) (wsb + 4096 + (size_t)NEXP*N_TOK*4);     // 1 MB
  ushort* w1t = (ushort*)(wsb + 4096 + (size_t)NEXP*N_TOK*8);     // 4 MB
  ushort* w2t = w1t + (size_t)NEXP * HID * DIM;                   // 4 MB
  float*  slab = (float*)(wsb + (size_t)(16 << 20));              // 32 MB @ +16MB

  bool use_slab = ws_size >= ((size_t)(16 << 20) + (size_t)N_TOK * DIM * 4);

  hipMemsetAsync(cnt, 0, NEXP * sizeof(int), stream);
  if (!use_slab)   // slab mode fully overwrites out; atomic fallback accumulates
    hipMemsetAsync(d_out, 0, (size_t)N_TOK * DIM * sizeof(float), stream);

  k_transpose_cast<<<dim3(HID/32, DIM/32, NEXP), dim3(32, 8), 0, stream>>>(W1, w1t, DIM, HID);
  k_transpose_cast<<<dim3(DIM/32, HID/32, NEXP), dim3(32, 8), 0, stream>>>(W2, w2t, HID, DIM);
  k_router<<<N_TOK/256, 256, 0, stream>>>(x, grad, Wr, br, probs, cnt, tok, wgt);
  if (use_slab) {
    k_moe<1><<<NEXP*MAXT, 256, 0, stream>>>(x, w1t, w2t, b1, b2, cnt, tok, wgt, out, slab);
    k_combine<<<2048, 256, 0, stream>>>(out, slab);
  } else {
    k_moe<0><<<NEXP*MAXT, 256, 0, stream>>>(x, w1t, w2t, b1, b2, cnt, tok, wgt, out, slab);
  }
}

// Round 20
// 216.749 us; speedup vs baseline: 1.0745x; 1.0051x over previous
//
#include <hip/hip_runtime.h>
#include <hip/hip_bf16.h>
#include <cmath>

#define N_TOK 32768
#define DIM   256
#define NEXP  8
#define HID   1024
#define BM    64
#define BH    64
#define MAXT  512   // MAXT*BM == N_TOK: covers worst-case expert load

typedef short bf16x8 __attribute__((ext_vector_type(8)));
typedef float f32x4  __attribute__((ext_vector_type(4)));

__device__ __forceinline__ ushort f2bf(float f) {
  unsigned u = __builtin_bit_cast(unsigned, f);
  u += 0x7fffu + ((u >> 16) & 1u);   // RNE
  return (ushort)(u >> 16);
}

// lh swizzle (128B rows): 16B-slot XOR, max 112 < 128 -> bijective in-row.
__device__ __forceinline__ int lh_slot(int row) {
  return ((row ^ (row >> 3)) & 7) << 4;
}
// lx swizzle (512B rows): (r&7)<<4, max 112 < 512, bijective.
__device__ __forceinline__ int lx_slot(int row) {
  return (row & 7) << 4;
}

// ---------- fused transpose+cast for BOTH weight tensors (one launch) ----------
// blocks 0..2047: W1 [E][256][1024] -> w1t [E][1024][256]
// blocks 2048..4095: W2 [E][1024][256] -> w2t [E][256][1024]
__global__ __launch_bounds__(256) void k_transpose_both(
    const float* __restrict__ W1, const float* __restrict__ W2,
    ushort* __restrict__ w1t, ushort* __restrict__ w2t)
{
  __shared__ float tile[32][33];
  int bid = blockIdx.x;
  int m = bid >> 11;                 // 0 = W1, 1 = W2
  int r2 = bid & 2047;
  int e = r2 >> 8;
  int t = r2 & 255;
  int R, C, rb, cb;
  const float* src;
  ushort* dst;
  if (m == 0) { R = DIM; C = HID; cb = t & 31; rb = t >> 5; src = W1; dst = w1t; }
  else        { R = HID; C = DIM; cb = t & 7;  rb = t >> 3; src = W2; dst = w2t; }
  const float* s = src + (size_t)e * R * C;
  ushort* d = dst + (size_t)e * R * C;
  int tx = threadIdx.x & 31, ty = threadIdx.x >> 5;   // 32 x 8
#pragma unroll
  for (int j = 0; j < 4; ++j)
    tile[ty + 8*j][tx] = s[(size_t)(rb*32 + ty + 8*j) * C + cb*32 + tx];
  __syncthreads();
#pragma unroll
  for (int j = 0; j < 4; ++j)
    d[(size_t)(cb*32 + ty + 8*j) * R + rb*32 + tx] = f2bf(tile[tx][ty + 8*j]);
}

// ---------- router: fp64 logits, softmax, top-2, bucket scatter ----------
// tok entry packs the top-k slot in bit 30: n | (slot<<30).
__global__ __launch_bounds__(256) void k_router(
    const float* __restrict__ x, const float* __restrict__ grad,
    const float* __restrict__ Wr, const float* __restrict__ br,
    float* __restrict__ probs_out,
    int* __restrict__ cnt, int* __restrict__ tok, float* __restrict__ wgt)
{
  __shared__ float xt[256][33];
  __shared__ float wrs[257*8];
  __shared__ float brs[8];
  __shared__ int lcnt[8], lbase[8];
  int tid = threadIdx.x;
  int n = blockIdx.x * 256 + tid;

  for (int i = tid; i < 257*8; i += 256) wrs[i] = Wr[i];
  if (tid < 8) { brs[tid] = br[tid]; lcnt[tid] = 0; }

  double acc[8] = {0,0,0,0,0,0,0,0};
  for (int ch = 0; ch < 8; ++ch) {
    __syncthreads();
    for (int f = tid; f < 2048; f += 256) {
      int r = f >> 3, c0 = (f & 7) * 4;
      float4 v = *(const float4*)(x + (size_t)(blockIdx.x*256 + r)*DIM + ch*32 + c0);
      xt[r][c0] = v.x; xt[r][c0+1] = v.y; xt[r][c0+2] = v.z; xt[r][c0+3] = v.w;
    }
    __syncthreads();
#pragma unroll 4
    for (int c = 0; c < 32; ++c) {
      double xv = (double)xt[tid][c];
      const float* wr = &wrs[(ch*32 + c)*8];
#pragma unroll
      for (int e = 0; e < 8; ++e) acc[e] += xv * (double)wr[e];
    }
  }
  double g = (double)grad[n];
  double lg[8];
#pragma unroll
  for (int e = 0; e < 8; ++e) lg[e] = acc[e] + g*(double)wrs[256*8+e] + (double)brs[e];
  double m = lg[0];
#pragma unroll
  for (int e = 1; e < 8; ++e) m = lg[e] > m ? lg[e] : m;
  double p[8], s = 0.0;
#pragma unroll
  for (int e = 0; e < 8; ++e) { p[e] = exp(lg[e]-m); s += p[e]; }
  double inv = 1.0/s;
#pragma unroll
  for (int e = 0; e < 8; ++e) probs_out[(size_t)n*8 + e] = (float)(p[e]*inv);

  int i0 = 0;
#pragma unroll
  for (int e = 1; e < 8; ++e) if (lg[e] > lg[i0]) i0 = e;
  int i1 = (i0 == 0) ? 1 : 0;
#pragma unroll
  for (int e = 0; e < 8; ++e) if (e != i0 && lg[e] > lg[i1]) i1 = e;
  float w0 = (float)(p[i0]*inv), w1 = (float)(p[i1]*inv);

  int p0 = atomicAdd(&lcnt[i0], 1);
  int p1 = atomicAdd(&lcnt[i1], 1);
  __syncthreads();
  if (tid < 8) lbase[tid] = atomicAdd(&cnt[tid], lcnt[tid]);
  __syncthreads();
  tok[i0*N_TOK + lbase[i0] + p0] = n;              wgt[i0*N_TOK + lbase[i0] + p0] = w0;
  tok[i1*N_TOK + lbase[i1] + p1] = n | (1 << 30);  wgt[i1*N_TOK + lbase[i1] + p1] = w1;
}

// ---------- fused gathered expert MLP ----------
// FINAL VALIDATED OPTIMUM (r17/r19: k_moe 167.7us, reproduced twice).
// Evidence ledger:
//  * (256,2): allocator gives 128 VGPR, zero spill. ANY occupancy-forcing
//    ((256,3), waves_per_eu(3,3)) makes it target 6 waves/EU -> 84 VGPR ->
//    scratch spills (FETCH 450 MB, 2.4x slower; r13/r14).
//  * 48 KB LDS does NOT raise residency (r18: occupancy flat, dbuf lost,
//    +17us) -> 80 KB double-buffered is strictly better.
//  * e = bid&7: weights L2-resident per XCD (FETCH 69->40 MB, r7).
//  * W1 staged via global_load_lds, double-buffered, issued at chunk top
//    (r9/r10: 321->188us with slab epilogue).
//  * GELU via 512-entry LDS LUT (r11: VALUBusy 42->21%, 188->168us).
//  * __syncthreads barriers; asm counted-vmcnt regressed (r12, +20us).
//  * setprio regressed on this lockstep structure (r15, +9us).
//  * wave-local-h restructure regressed (r16: serial bpermute chain, ~400us).
template<int SLAB>
__global__ __launch_bounds__(256, 2) void k_moe(
    const float* __restrict__ x,
    const ushort* __restrict__ w1t,   // [E][H][D] bf16 (transposed)
    const ushort* __restrict__ w2t,   // [E][D][H] bf16 (transposed)
    const float* __restrict__ bias1,  // [E][H]
    const float* __restrict__ bias2,  // [E][D]
    const int* __restrict__ cnt, const int* __restrict__ tok,
    const float* __restrict__ wgt,
    float* __restrict__ out, float* __restrict__ slab)
{
  int e    = blockIdx.x & 7;
  int tile = blockIdx.x >> 3;
  int c = cnt[e];
  int row0 = tile * BM;
  if (row0 >= c) return;
  int rows = min(BM, c - row0);
  int phase = tile & 15;              // stagger concurrent blocks across W chunks

  __shared__ ushort lsA[BM * DIM];    // 32 KB: x tile, then W1 buffer (odd chunks)
  __shared__ ushort lsB[BH * DIM];    // 32 KB: W1 buffer (even chunks)
  __shared__ ushort lh[BM * BH];      // 8 KB h tile
  __shared__ float  lb1[HID];         // 4 KB bias1
  __shared__ float2 lut[512];         // 4 KB gelu LUT: g(v) ~= a + b*v, v in [-8,8]
  // total 80 KB -> 2 blocks/CU

  int tid  = threadIdx.x;
  int lane = tid & 63;
  int wid  = tid >> 6;
  const int l15 = lane & 15;
  const int lk8 = (lane >> 4) * 8;
  const int lr4 = (lane >> 4) * 4;
  const int wr = wid >> 1, wc = wid & 1;   // 2x2 wave grid for GEMM1

  const int*   etok = tok + e * N_TOK + row0;
  const float* ewgt = wgt + e * N_TOK + row0;
  const ushort* W1e = w1t + (size_t)e * HID * DIM;
  const ushort* W2e = w2t + (size_t)e * DIM * HID;

  // ---- prologue: x -> lsA (swizzled), bias1 -> lb1, LUT, W1 chunk0 -> lsB ----
  for (int f = tid; f < BM * (DIM/4); f += 256) {
    int r = f >> 6, c4 = f & 63;
    int t = etok[min(r, rows - 1)] & 0xFFFF;
    float4 v = *(const float4*)(x + (size_t)t * DIM + c4 * 4);
    ushort4 b;
    b.x = f2bf(v.x); b.y = f2bf(v.y); b.z = f2bf(v.z); b.w = f2bf(v.w);
    *(ushort4*)((char*)lsA + r * 512 + ((c4 * 8) ^ lx_slot(r))) = b;
  }
#pragma unroll
  for (int i = 0; i < 4; ++i) lb1[i*256 + tid] = bias1[e*HID + i*256 + tid];
  // gelu LUT: segment i covers [v0, v0+1/32), chord endpoints -> exact at knots
  for (int i = tid; i < 512; i += 256) {
    float v0 = i * 0.03125f - 8.0f;
    float v1 = v0 + 0.03125f;
    float g0 = 0.5f * v0 * (1.0f + erff(v0 * 0.70710678f));
    float g1 = 0.5f * v1 * (1.0f + erff(v1 * 0.70710678f));
    float b  = (g1 - g0) * 32.0f;
    lut[i] = make_float2(g0 - b * v0, b);
  }
  {
    int h0 = (phase & 15) * BH;
#pragma unroll
    for (int i = 0; i < 8; ++i) {
      int u = i*256 + tid;
      int r = u >> 5, s = u & 31;
      const ushort* g = W1e + (size_t)(h0 + r) * DIM + ((s ^ (r & 7)) * 8);
      __builtin_amdgcn_global_load_lds(
          (const __attribute__((address_space(1))) unsigned int*)g,
          (__attribute__((address_space(3))) unsigned int*)(lsB + u*8),
          16, 0, 0);
    }
  }
  __syncthreads();   // full drain: x, LUT, bias, W1 chunk0 all visible

  // ---- hoist A-fragments to registers once ----
  bf16x8 areg[2][8];
#pragma unroll
  for (int fr = 0; fr < 2; ++fr) {
    int row = wr*32 + fr*16 + l15;
#pragma unroll
    for (int k = 0; k < 8; ++k)
      areg[fr][k] = *(const bf16x8*)((const char*)lsA + row*512
                      + (((k*32 + lk8)*2) ^ lx_slot(row)));
  }
  __syncthreads();   // all waves' areg reads done before lsA is restaged as W1

  f32x4 accY[4][4];
#pragma unroll
  for (int i = 0; i < 4; ++i)
#pragma unroll
    for (int j = 0; j < 4; ++j) accY[i][j] = (f32x4){0.f,0.f,0.f,0.f};

  int sl2[4];
#pragma unroll
  for (int fr = 0; fr < 4; ++fr) sl2[fr] = lh_slot(fr*16 + l15);

  // W1 LDS fragment addressing (ushort units): unit = row*32 + (s ^ (row&7))
  const int b0row = wc*32 + l15;            // b1 row = b0row+16, same (row&7)
  const int bxor  = (b0row & 7);

  for (int cc = 0; cc < HID / BH; ++cc) {
    int chunk = (cc + phase) & 15;
    int h0 = chunk * BH;
    ushort* cur = (cc & 1) ? lsA : lsB;
    ushort* nxt = (cc & 1) ? lsB : lsA;

    // W2 B-fragments to regs (consumed after barrier A -> latency covered)
    bf16x8 bw[2][4];
#pragma unroll
    for (int k2 = 0; k2 < 2; ++k2)
#pragma unroll
      for (int fc = 0; fc < 4; ++fc)
        bw[k2][fc] = *(const bf16x8*)(W2e + (size_t)(wid*64 + fc*16 + l15) * HID
                                      + h0 + k2*32 + lk8);

    // stage W1 for chunk cc+1 (drains at barrier A with the chunk's other vm
    // ops; covered by GEMM1 + GELU)
    if (cc < HID/BH - 1) {
      int nh0 = ((cc + 1 + phase) & 15) * BH;
#pragma unroll
      for (int i = 0; i < 8; ++i) {
        int u = i*256 + tid;
        int r = u >> 5, s = u & 31;
        const ushort* g = W1e + (size_t)(nh0 + r) * DIM + ((s ^ (r & 7)) * 8);
        __builtin_amdgcn_global_load_lds(
            (const __attribute__((address_space(1))) unsigned int*)g,
            (__attribute__((address_space(3))) unsigned int*)(nxt + u*8),
            16, 0, 0);
      }
    }

    f32x4 accH[2][2];
#pragma unroll
    for (int i = 0; i < 2; ++i)
#pragma unroll
      for (int j = 0; j < 2; ++j) accH[i][j] = (f32x4){0.f,0.f,0.f,0.f};

    // GEMM1: h[64x64] = x[64x256] @ W1[256x64]; B from cur (conflict-free)
#pragma unroll
    for (int k = 0; k < 8; ++k) {
      int s = k*4 + (lane >> 4);
      bf16x8 b0 = *(const bf16x8*)(cur + ((b0row     )*32 + (s ^ bxor))*8);
      bf16x8 b1 = *(const bf16x8*)(cur + ((b0row + 16)*32 + (s ^ bxor))*8);
      accH[0][0] = __builtin_amdgcn_mfma_f32_16x16x32_bf16(areg[0][k], b0, accH[0][0], 0, 0, 0);
      accH[1][0] = __builtin_amdgcn_mfma_f32_16x16x32_bf16(areg[1][k], b0, accH[1][0], 0, 0, 0);
      accH[0][1] = __builtin_amdgcn_mfma_f32_16x16x32_bf16(areg[0][k], b1, accH[0][1], 0, 0, 0);
      accH[1][1] = __builtin_amdgcn_mfma_f32_16x16x32_bf16(areg[1][k], b1, accH[1][1], 0, 0, 0);
    }

    // GELU (LUT) + bf16 -> swizzled lh
#pragma unroll
    for (int fc = 0; fc < 2; ++fc) {
      int col = wc*32 + fc*16 + l15;
      float bv = lb1[h0 + col];
#pragma unroll
      for (int fr = 0; fr < 2; ++fr)
#pragma unroll
        for (int j = 0; j < 4; ++j) {
          int row = wr*32 + fr*16 + lr4 + j;
          float v = accH[fr][fc][j] + bv;
          int idx = (int)(v * 32.0f + 256.0f);
          idx = min(max(idx, 0), 511);
          float2 ab = lut[idx];
          float g = fmaf(ab.y, v, ab.x);
          *(ushort*)((char*)lh + row*128 + ((col*2) ^ lh_slot(row))) = f2bf(g);
        }
    }
    __syncthreads();   // barrier A: lh visible; stage + bw drained (covered)

    // GEMM2: y[64x256] += h[64x64] @ W2[64x256]
#pragma unroll
    for (int k2 = 0; k2 < 2; ++k2) {
      bf16x8 a2[4];
#pragma unroll
      for (int fr = 0; fr < 4; ++fr) {
        int row = fr*16 + l15;
        a2[fr] = *(const bf16x8*)((const char*)lh + row*128 + (((k2*32 + lk8)*2) ^ sl2[fr]));
      }
#pragma unroll
      for (int fr = 0; fr < 4; ++fr)
#pragma unroll
        for (int fc = 0; fc < 4; ++fc)
          accY[fr][fc] = __builtin_amdgcn_mfma_f32_16x16x32_bf16(a2[fr], bw[k2][fc], accY[fr][fc], 0, 0, 0);
    }
    __syncthreads();   // barrier B: lh reusable (vm-free -> cheap)
  }

  // epilogue: contribution = w * (y + b2)
  float b2v[4];
#pragma unroll
  for (int fc = 0; fc < 4; ++fc) b2v[fc] = bias2[e*DIM + wid*64 + fc*16 + l15];
#pragma unroll
  for (int fr = 0; fr < 4; ++fr) {
#pragma unroll
    for (int j = 0; j < 4; ++j) {
      int r = fr*16 + lr4 + j;
      if (r < rows) {
        int raw = etok[r];
        int t   = raw & 0xFFFF;
        float w = ewgt[r];
        if (SLAB) {
          // each (token,slot) written by exactly one block -> plain stores;
          // out (slot0) and slab (slot1) are FULLY covered -> no memset needed
          float* dst = ((raw >> 30) ? slab : out) + (size_t)t * DIM;
#pragma unroll
          for (int fc = 0; fc < 4; ++fc)
            dst[wid*64 + fc*16 + l15] = w * (accY[fr][fc][j] + b2v[fc]);
        } else {
#pragma unroll
          for (int fc = 0; fc < 4; ++fc)
            atomicAdd(out + (size_t)t * DIM + wid*64 + fc*16 + l15,
                      w * (accY[fr][fc][j] + b2v[fc]));
        }
      }
    }
  }
}

// out += slab (slab fully written: every token has exactly one slot-1 entry)
__global__ __launch_bounds__(256) void k_combine(
    float* __restrict__ out, const float* __restrict__ slab)
{
  int stride = gridDim.x * blockDim.x;
  for (int i = blockIdx.x * blockDim.x + threadIdx.x;
       i < N_TOK * DIM / 4; i += stride) {
    float4 a = ((const float4*)out)[i];
    float4 b = ((const float4*)slab)[i];
    a.x += b.x; a.y += b.y; a.z += b.z; a.w += b.w;
    ((float4*)out)[i] = a;
  }
}

extern "C" void kernel_launch(void* const* d_in, const int* in_sizes, int n_in,
                              void* d_out, int out_size, void* d_ws, size_t ws_size,
                              hipStream_t stream)
{
  const float* x    = (const float*)d_in[0];
  const float* grad = (const float*)d_in[1];
  const float* Wr   = (const float*)d_in[2];
  const float* br   = (const float*)d_in[3];
  const float* W1   = (const float*)d_in[4];
  const float* b1   = (const float*)d_in[5];
  const float* W2   = (const float*)d_in[6];
  const float* b2   = (const float*)d_in[7];
  float* out   = (float*)d_out;
  float* probs = out + (size_t)N_TOK * DIM;

  char* wsb = (char*)d_ws;
  int*    cnt = (int*)wsb;                                        // 32 B
  int*    tok = (int*)   (wsb + 4096);                            // 1 MB
  float*  wgt = (float*) (wsb + 4096 + (size_t)NEXP*N_TOK*4);     // 1 MB
  ushort* w1t = (ushort*)(wsb + 4096 + (size_t)NEXP*N_TOK*8);     // 4 MB
  ushort* w2t = w1t + (size_t)NEXP * HID * DIM;                   // 4 MB
  float*  slab = (float*)(wsb + (size_t)(16 << 20));              // 32 MB @ +16MB

  bool use_slab = ws_size >= ((size_t)(16 << 20) + (size_t)N_TOK * DIM * 4);

  hipMemsetAsync(cnt, 0, NEXP * sizeof(int), stream);
  if (!use_slab)   // slab mode fully overwrites out; atomic fallback accumulates
    hipMemsetAsync(d_out, 0, (size_t)N_TOK * DIM * sizeof(float), stream);

  k_transpose_both<<<4096, 256, 0, stream>>>(W1, W2, w1t, w2t);
  k_router<<<N_TOK/256, 256, 0, stream>>>(x, grad, Wr, br, probs, cnt, tok, wgt);
  if (use_slab) {
    k_moe<1><<<NEXP*MAXT, 256, 0, stream>>>(x, w1t, w2t, b1, b2, cnt, tok, wgt, out, slab);
    k_combine<<<2048, 256, 0, stream>>>(out, slab);
  } else {
    k_moe<0><<<NEXP*MAXT, 256, 0, stream>>>(x, w1t, w2t, b1, b2, cnt, tok, wgt, out, slab);
  }
}